// Round 8
// baseline (849.932 us; speedup 1.0000x reference)
//
#include <hip/hip_runtime.h>
#include <hip/hip_bf16.h>

using bf16x8 = __attribute__((ext_vector_type(8))) short;
using f32x4  = __attribute__((ext_vector_type(4))) float;
using u16x4  = __attribute__((ext_vector_type(4))) unsigned short;

constexpr int Ht = 60, Wt = 108, C = 512;
constexpr int GWt = 14, NWIN = 112, NTOK = Ht * Wt, BT = 16;
constexpr int NBLK = BT * NWIN;                   // 1792 window blocks
constexpr float SCALE = 0.08838834764831845f;     // 1/sqrt(128)
constexpr size_t WOFF = 4 * 262144;               // weights: 4x512x512 bf16 elems
constexpr size_t SLABE = (size_t)NBLK * 64 * 512; // attn slab elems (bf16)

__device__ __forceinline__ unsigned short f2b(float f) {   // f32 -> bf16 RNE
  union { float f; unsigned u; } v; v.f = f;
  unsigned r = v.u + 0x7fffu + ((v.u >> 16) & 1u);
  return (unsigned short)(r >> 16);
}

__global__ void cvt_weights(const float* __restrict__ a, const float* __restrict__ b,
                            const float* __restrict__ c, const float* __restrict__ d,
                            unsigned short* __restrict__ dst) {
  int i = blockIdx.x * blockDim.x + threadIdx.x;   // 262144 threads, 4 f32 each
  int m  = i >> 16;
  int o4 = i & 65535;
  const float* src = (m == 0) ? a : (m == 1) ? b : (m == 2) ? c : d;
  float4 v = *(const float4*)(src + (size_t)o4 * 4);
  u16x4 o;
  o[0] = f2b(v.x); o[1] = f2b(v.y); o[2] = f2b(v.z); o[3] = f2b(v.w);
  *(u16x4*)(dst + (size_t)m * 262144 + (size_t)o4 * 4) = o;
}

// ---- K1: per-window QKV + attention -> bf16 attn slab [blk][64][512] in ws --
// LDS 72KB: XL [64][256] 32K @0 | qb 16K @32768 | kb 16K @49152 | pb 8K @65536
// (high x half bounced through qb+kb region into 32 persistent VGPRs)
extern "C" __global__ __launch_bounds__(256, 1)
void qkv_attn(const float* __restrict__ x,
              const unsigned short* __restrict__ wbf,   // [4][512][512] bf16
              const float* __restrict__ bq, const float* __restrict__ bk,
              const float* __restrict__ bv,
              unsigned short* __restrict__ slab)
{
  __shared__ char smem[73728];
  char* qb = smem + 32768;
  char* kb = smem + 49152;
  char* pb = smem + 65536;

  const int tid   = threadIdx.x;
  const int wvid  = tid >> 6;
  const int lane  = tid & 63;
  const int l15   = lane & 15;
  const int kl    = (lane >> 4) << 3;
  const int rbase = (lane >> 4) << 2;

  const int blk = blockIdx.x;
  const int b   = blk / NWIN;
  const int w   = blk - b * NWIN;
  const int wy  = w / GWt, wx = w - wy * GWt;

  // ---- stage x window: low half -> XL (resident), high half -> bounce ----
  for (int it = 0; it < 32; ++it) {
    int f  = it * 256 + tid;           // u16x4 group; 128 per row
    int r  = f >> 7;
    int c4 = f & 127;
    int gy = wy * 8 + (r >> 3), gx = wx * 8 + (r & 7);
    float4 v = make_float4(0.f, 0.f, 0.f, 0.f);
    if (gy < Ht && gx < Wt)
      v = *(const float4*)(x + ((size_t)b * NTOK + gy * Wt + gx) * C + c4 * 4);
    u16x4 o;
    o[0] = f2b(v.x); o[1] = f2b(v.y); o[2] = f2b(v.z); o[3] = f2b(v.w);
    int lc  = c4 & 63;                 // col group within half
    int off = (r << 9) + (lc << 3);
    off ^= (r & 7) << 4;
    off += (c4 >> 6) * 32768;          // half 0 -> @0, half 1 -> bounce @32768
    *(u16x4*)(smem + off) = o;
  }
  __syncthreads();

  // high-half A-fragments -> 32 persistent VGPRs
  bf16x8 xr[4][8];
  #pragma unroll
  for (int mt = 0; mt < 4; ++mt) {
    int row = mt * 16 + l15;
    #pragma unroll
    for (int s = 0; s < 8; ++s) {
      int off = (row << 9) + ((s * 32 + kl) << 1);
      off ^= (row & 7) << 4;
      xr[mt][s] = *(const bf16x8*)(smem + 32768 + off);
    }
  }
  __syncthreads();                     // bounce region becomes qb/kb

  auto store_rm = [&](f32x4 (&acc)[4][2], char* base, const float* bias, int h) {
    #pragma unroll
    for (int nt = 0; nt < 2; ++nt) {
      int col = wvid * 32 + nt * 16 + l15;
      float bi = bias[h * 128 + col];
      #pragma unroll
      for (int mt = 0; mt < 4; ++mt)
        #pragma unroll
        for (int rg = 0; rg < 4; ++rg) {
          int row = mt * 16 + rbase + rg;
          int off = (row << 8) + (col << 1);
          off ^= (row & 7) << 4;
          *(unsigned short*)(base + off) = f2b(acc[mt][nt][rg] + bi);
        }
    }
  };

  unsigned short* sl = slab + (size_t)blk * 32768;   // [64][512] bf16

  const unsigned short* wq = wbf + 0 * 262144;
  const unsigned short* wk = wbf + 1 * 262144;
  const unsigned short* wv = wbf + 2 * 262144;

  for (int h = 0; h < 4; ++h) {
    f32x4 vacc[4][2];                  // V result, regs through softmax
    // ---- Phase A: merged Q,K,V gemm (one k-pass, 3 accumulators) ----
    {
      f32x4 aq[4][2], ak[4][2];
      #pragma unroll
      for (int mt = 0; mt < 4; ++mt)
        #pragma unroll
        for (int nt = 0; nt < 2; ++nt) {
          aq[mt][nt]   = (f32x4){0.f, 0.f, 0.f, 0.f};
          ak[mt][nt]   = (f32x4){0.f, 0.f, 0.f, 0.f};
          vacc[mt][nt] = (f32x4){0.f, 0.f, 0.f, 0.f};
        }
      #pragma unroll
      for (int s = 0; s < 16; ++s) {
        int ka = s * 32 + kl;
        bf16x8 afr[4];
        if (s < 8) {
          #pragma unroll
          for (int mt = 0; mt < 4; ++mt) {
            int row = mt * 16 + l15;
            int off = (row << 9) + (ka << 1);
            off ^= (row & 7) << 4;
            afr[mt] = *(const bf16x8*)(smem + off);
          }
        } else {
          #pragma unroll
          for (int mt = 0; mt < 4; ++mt) afr[mt] = xr[mt][s - 8];
        }
        bf16x8 bq_[2], bk_[2], bv_[2];
        #pragma unroll
        for (int nt = 0; nt < 2; ++nt) {
          size_t jg = (size_t)(h * 128 + wvid * 32 + nt * 16 + l15) * 512 + ka;
          bq_[nt] = *(const bf16x8*)(wq + jg);
          bk_[nt] = *(const bf16x8*)(wk + jg);
          bv_[nt] = *(const bf16x8*)(wv + jg);
        }
        #pragma unroll
        for (int mt = 0; mt < 4; ++mt)
          #pragma unroll
          for (int nt = 0; nt < 2; ++nt) {
            aq[mt][nt]   = __builtin_amdgcn_mfma_f32_16x16x32_bf16(afr[mt], bq_[nt], aq[mt][nt], 0, 0, 0);
            ak[mt][nt]   = __builtin_amdgcn_mfma_f32_16x16x32_bf16(afr[mt], bk_[nt], ak[mt][nt], 0, 0, 0);
            vacc[mt][nt] = __builtin_amdgcn_mfma_f32_16x16x32_bf16(afr[mt], bv_[nt], vacc[mt][nt], 0, 0, 0);
          }
      }
      store_rm(aq, qb, bq, h);
      store_rm(ak, kb, bk, h);
    }
    __syncthreads();
    // ---- Phase B: QK^T + softmax -> P ----
    {
      f32x4 sacc[4];
      #pragma unroll
      for (int nt = 0; nt < 4; ++nt) sacc[nt] = (f32x4){0.f, 0.f, 0.f, 0.f};
      #pragma unroll
      for (int kk = 0; kk < 128; kk += 32) {
        int ka = kk + kl;
        int row = wvid * 16 + l15;
        int off = (row << 8) + (ka << 1); off ^= (row & 7) << 4;
        bf16x8 afr = *(const bf16x8*)(qb + off);
        #pragma unroll
        for (int nt = 0; nt < 4; ++nt) {
          int jr = nt * 16 + l15;
          int o2 = (jr << 8) + (ka << 1); o2 ^= (jr & 7) << 4;
          bf16x8 bfr = *(const bf16x8*)(kb + o2);
          sacc[nt] = __builtin_amdgcn_mfma_f32_16x16x32_bf16(afr, bfr, sacc[nt], 0, 0, 0);
        }
      }
      #pragma unroll
      for (int rg = 0; rg < 4; ++rg) {
        float m = -3.0e38f;
        #pragma unroll
        for (int nt = 0; nt < 4; ++nt) m = fmaxf(m, sacc[nt][rg]);
        #pragma unroll
        for (int dd = 1; dd < 16; dd <<= 1) m = fmaxf(m, __shfl_xor(m, dd, 64));
        float s = 0.f, e[4];
        #pragma unroll
        for (int nt = 0; nt < 4; ++nt) { e[nt] = __expf((sacc[nt][rg] - m) * SCALE); s += e[nt]; }
        #pragma unroll
        for (int dd = 1; dd < 16; dd <<= 1) s += __shfl_xor(s, dd, 64);
        float inv = 1.f / s;
        int row = wvid * 16 + rbase + rg;
        #pragma unroll
        for (int nt = 0; nt < 4; ++nt) {
          int col = nt * 16 + l15;
          int off = (row << 7) + (col << 1); off ^= (row & 7) << 4;
          *(unsigned short*)(pb + off) = f2b(e[nt] * inv);
        }
      }
    }
    __syncthreads();
    // ---- Phase C: Vt (from regs) over dead K buffer ----
    {
      #pragma unroll
      for (int nt = 0; nt < 2; ++nt) {
        int d = wvid * 32 + nt * 16 + l15;
        float bi = bv[h * 128 + d];
        #pragma unroll
        for (int mt = 0; mt < 4; ++mt) {
          int j0 = mt * 16 + rbase;
          u16x4 pk;
          #pragma unroll
          for (int rg = 0; rg < 4; ++rg) pk[rg] = f2b(vacc[mt][nt][rg] + bi);
          int off = (d << 7) + (j0 << 1); off ^= (d & 7) << 4;
          *(u16x4*)(kb + off) = pk;
        }
      }
    }
    __syncthreads();
    // ---- Phase D: attn_h = P @ V -> bf16 slab (head's 128 cols) ----
    {
      f32x4 pacc[4][2];
      #pragma unroll
      for (int mt = 0; mt < 4; ++mt)
        #pragma unroll
        for (int nt = 0; nt < 2; ++nt) pacc[mt][nt] = (f32x4){0.f, 0.f, 0.f, 0.f};
      #pragma unroll
      for (int kk = 0; kk < 64; kk += 32) {
        int ka = kk + kl;
        bf16x8 afr[4];
        #pragma unroll
        for (int mt = 0; mt < 4; ++mt) {
          int row = mt * 16 + l15;
          int off = (row << 7) + (ka << 1); off ^= (row & 7) << 4;
          afr[mt] = *(const bf16x8*)(pb + off);
        }
        bf16x8 bfr[2];
        #pragma unroll
        for (int nt = 0; nt < 2; ++nt) {
          int d = wvid * 32 + nt * 16 + l15;
          int off = (d << 7) + (ka << 1); off ^= (d & 7) << 4;
          bfr[nt] = *(const bf16x8*)(kb + off);
        }
        #pragma unroll
        for (int mt = 0; mt < 4; ++mt)
          #pragma unroll
          for (int nt = 0; nt < 2; ++nt)
            pacc[mt][nt] = __builtin_amdgcn_mfma_f32_16x16x32_bf16(afr[mt], bfr[nt], pacc[mt][nt], 0, 0, 0);
      }
      #pragma unroll
      for (int nt = 0; nt < 2; ++nt) {
        int d = wvid * 32 + nt * 16 + l15;
        #pragma unroll
        for (int mt = 0; mt < 4; ++mt)
          #pragma unroll
          for (int rg = 0; rg < 4; ++rg) {
            int row = mt * 16 + rbase + rg;
            sl[row * 512 + h * 128 + d] = f2b(pacc[mt][nt][rg]);
          }
      }
    }
    __syncthreads();   // kb/pb reads done before next head rewrites qb/kb
  }
}

// ---- K2: out = slab @ Wo^T + bo  (reads slab, writes out; NOT in-place) ----
extern "C" __global__ __launch_bounds__(256, 1)
void proj_o(const unsigned short* __restrict__ slab,
            const unsigned short* __restrict__ wo,
            const float* __restrict__ bo,
            float* __restrict__ out)
{
  __shared__ char smem[65536];                 // [64][512] bf16, swizzled
  const int tid   = threadIdx.x;
  const int wvid  = tid >> 6;
  const int lane  = tid & 63;
  const int l15   = lane & 15;
  const int kl    = (lane >> 4) << 3;
  const int rbase = (lane >> 4) << 2;

  const int blk = blockIdx.x;
  const int b   = blk / NWIN;
  const int w   = blk - b * NWIN;
  const int wy  = w / GWt, wx = w - wy * GWt;

  const unsigned short* src = slab + (size_t)blk * 32768;
  for (int it = 0; it < 16; ++it) {
    int f  = it * 256 + tid;                   // u16x8 group; 64 per row
    int r  = f >> 6;
    int c8 = f & 63;
    bf16x8 v = *(const bf16x8*)(src + r * 512 + c8 * 8);
    int off = (r << 10) + (c8 << 4);
    off ^= (r & 7) << 4;
    *(bf16x8*)(smem + off) = v;
  }
  __syncthreads();

  for (int half = 0; half < 2; ++half) {
    f32x4 acc[4][4];
    #pragma unroll
    for (int mt = 0; mt < 4; ++mt)
      #pragma unroll
      for (int nt = 0; nt < 4; ++nt) acc[mt][nt] = (f32x4){0.f, 0.f, 0.f, 0.f};
    #pragma unroll 2
    for (int kk = 0; kk < 512; kk += 32) {
      int ka = kk + kl;
      bf16x8 afr[4];
      #pragma unroll
      for (int mt = 0; mt < 4; ++mt) {
        int row = mt * 16 + l15;
        int off = (row << 10) + (ka << 1); off ^= (row & 7) << 4;
        afr[mt] = *(const bf16x8*)(smem + off);
      }
      bf16x8 bfr[4];
      #pragma unroll
      for (int nt = 0; nt < 4; ++nt) {
        int j = wvid * 128 + half * 64 + nt * 16 + l15;
        bfr[nt] = *(const bf16x8*)(wo + (size_t)j * 512 + ka);
      }
      #pragma unroll
      for (int mt = 0; mt < 4; ++mt)
        #pragma unroll
        for (int nt = 0; nt < 4; ++nt)
          acc[mt][nt] = __builtin_amdgcn_mfma_f32_16x16x32_bf16(afr[mt], bfr[nt], acc[mt][nt], 0, 0, 0);
    }
    #pragma unroll
    for (int mt = 0; mt < 4; ++mt)
      #pragma unroll
      for (int rg = 0; rg < 4; ++rg) {
        int r = mt * 16 + rbase + rg;
        int gy = wy * 8 + (r >> 3), gx = wx * 8 + (r & 7);
        if (gy < Ht && gx < Wt) {
          float* po = out + ((size_t)b * NTOK + gy * Wt + gx) * C;
          #pragma unroll
          for (int nt = 0; nt < 4; ++nt) {
            int j = wvid * 128 + half * 64 + nt * 16 + l15;
            po[j] = acc[mt][nt][rg] + bo[j];
          }
        }
      }
  }
}

// ---------------- fallback: proven round-1 monolithic kernel ----------------
constexpr int M_XW = 0, M_AB = 65536, M_KV = 131072, M_P = 147456;
constexpr int M_LDS = 155648;

extern "C" __global__ __launch_bounds__(256, 1)
void swmhsa_mono(const float* __restrict__ x,
                 const unsigned short* __restrict__ wqkvo,
                 const float* __restrict__ bq, const float* __restrict__ bk,
                 const float* __restrict__ bv, const float* __restrict__ bo,
                 float* __restrict__ out)
{
  extern __shared__ char smem[];
  const int tid   = threadIdx.x;
  const int wvid  = tid >> 6;
  const int lane  = tid & 63;
  const int l15   = lane & 15;
  const int kl    = (lane >> 4) << 3;
  const int rbase = (lane >> 4) << 2;

  const int blk = blockIdx.x;
  const int b   = blk / NWIN;
  const int w   = blk - b * NWIN;
  const int wy  = w / GWt, wx = w - wy * GWt;

  for (int it = 0; it < 32; ++it) {
    int f  = it * 256 + tid;
    int r  = f >> 7;
    int c4 = f & 127;
    int gy = wy * 8 + (r >> 3), gx = wx * 8 + (r & 7);
    float4 v = make_float4(0.f, 0.f, 0.f, 0.f);
    if (gy < Ht && gx < Wt)
      v = *(const float4*)(x + ((size_t)b * NTOK + gy * Wt + gx) * C + c4 * 4);
    u16x4 o;
    o[0] = f2b(v.x); o[1] = f2b(v.y); o[2] = f2b(v.z); o[3] = f2b(v.w);
    int off = (r << 10) + (c4 << 3);
    off ^= (r & 7) << 4;
    *(u16x4*)(smem + M_XW + off) = o;
  }
  __syncthreads();

  auto gemm_qkv = [&](const unsigned short* wm, int h, f32x4 (&acc)[4][2]) {
    #pragma unroll
    for (int mt = 0; mt < 4; ++mt)
      #pragma unroll
      for (int nt = 0; nt < 2; ++nt) acc[mt][nt] = (f32x4){0.f, 0.f, 0.f, 0.f};
    for (int kk = 0; kk < 512; kk += 32) {
      int ka = kk + kl;
      bf16x8 afr[4];
      #pragma unroll
      for (int mt = 0; mt < 4; ++mt) {
        int row = mt * 16 + l15;
        int off = (row << 10) + (ka << 1);
        off ^= (row & 7) << 4;
        afr[mt] = *(const bf16x8*)(smem + M_XW + off);
      }
      bf16x8 bfr[2];
      #pragma unroll
      for (int nt = 0; nt < 2; ++nt) {
        int jg = h * 128 + wvid * 32 + nt * 16 + l15;
        bfr[nt] = *(const bf16x8*)(wm + (size_t)jg * 512 + ka);
      }
      #pragma unroll
      for (int mt = 0; mt < 4; ++mt)
        #pragma unroll
        for (int nt = 0; nt < 2; ++nt)
          acc[mt][nt] = __builtin_amdgcn_mfma_f32_16x16x32_bf16(afr[mt], bfr[nt], acc[mt][nt], 0, 0, 0);
    }
  };

  auto store_rm = [&](f32x4 (&acc)[4][2], char* base, const float* bias, int h) {
    #pragma unroll
    for (int nt = 0; nt < 2; ++nt) {
      int col = wvid * 32 + nt * 16 + l15;
      float bi = bias[h * 128 + col];
      #pragma unroll
      for (int mt = 0; mt < 4; ++mt)
        #pragma unroll
        for (int rg = 0; rg < 4; ++rg) {
          int row = mt * 16 + rbase + rg;
          int off = (row << 8) + (col << 1);
          off ^= (row & 7) << 4;
          *(unsigned short*)(base + off) = f2b(acc[mt][nt][rg] + bi);
        }
    }
  };

  for (int h = 0; h < 4; ++h) {
    char* ab = smem + M_AB + h * 16384;
    {
      f32x4 acc[4][2];
      gemm_qkv(wqkvo + 1 * 262144, h, acc);
      store_rm(acc, smem + M_KV, bk, h);
      gemm_qkv(wqkvo + 0 * 262144, h, acc);
      store_rm(acc, ab, bq, h);
    }
    __syncthreads();
    {
      f32x4 sacc[4];
      #pragma unroll
      for (int nt = 0; nt < 4; ++nt) sacc[nt] = (f32x4){0.f, 0.f, 0.f, 0.f};
      #pragma unroll
      for (int kk = 0; kk < 128; kk += 32) {
        int ka = kk + kl;
        int row = wvid * 16 + l15;
        int off = (row << 8) + (ka << 1); off ^= (row & 7) << 4;
        bf16x8 afr = *(const bf16x8*)(ab + off);
        #pragma unroll
        for (int nt = 0; nt < 4; ++nt) {
          int jr = nt * 16 + l15;
          int o2 = (jr << 8) + (ka << 1); o2 ^= (jr & 7) << 4;
          bf16x8 bfr = *(const bf16x8*)(smem + M_KV + o2);
          sacc[nt] = __builtin_amdgcn_mfma_f32_16x16x32_bf16(afr, bfr, sacc[nt], 0, 0, 0);
        }
      }
      #pragma unroll
      for (int rg = 0; rg < 4; ++rg) {
        float m = -3.0e38f;
        #pragma unroll
        for (int nt = 0; nt < 4; ++nt) m = fmaxf(m, sacc[nt][rg]);
        #pragma unroll
        for (int dd = 1; dd < 16; dd <<= 1) m = fmaxf(m, __shfl_xor(m, dd, 64));
        float s = 0.f, e[4];
        #pragma unroll
        for (int nt = 0; nt < 4; ++nt) { e[nt] = __expf((sacc[nt][rg] - m) * SCALE); s += e[nt]; }
        #pragma unroll
        for (int dd = 1; dd < 16; dd <<= 1) s += __shfl_xor(s, dd, 64);
        float inv = 1.f / s;
        int row = wvid * 16 + rbase + rg;
        #pragma unroll
        for (int nt = 0; nt < 4; ++nt) {
          int col = nt * 16 + l15;
          int off = (row << 7) + (col << 1); off ^= (row & 7) << 4;
          *(unsigned short*)(smem + M_P + off) = f2b(e[nt] * inv);
        }
      }
    }
    __syncthreads();
    {
      f32x4 vacc[4][2];
      gemm_qkv(wqkvo + 2 * 262144, h, vacc);
      #pragma unroll
      for (int nt = 0; nt < 2; ++nt) {
        int d = wvid * 32 + nt * 16 + l15;
        float bi = bv[h * 128 + d];
        #pragma unroll
        for (int mt = 0; mt < 4; ++mt) {
          int j0 = mt * 16 + rbase;
          u16x4 pk;
          #pragma unroll
          for (int rg = 0; rg < 4; ++rg) pk[rg] = f2b(vacc[mt][nt][rg] + bi);
          int off = (d << 7) + (j0 << 1); off ^= (d & 7) << 4;
          *(u16x4*)(smem + M_KV + off) = pk;
        }
      }
    }
    __syncthreads();
    {
      f32x4 pacc[4][2];
      #pragma unroll
      for (int mt = 0; mt < 4; ++mt)
        #pragma unroll
        for (int nt = 0; nt < 2; ++nt) pacc[mt][nt] = (f32x4){0.f, 0.f, 0.f, 0.f};
      #pragma unroll
      for (int kk = 0; kk < 64; kk += 32) {
        int ka = kk + kl;
        bf16x8 afr[4];
        #pragma unroll
        for (int mt = 0; mt < 4; ++mt) {
          int row = mt * 16 + l15;
          int off = (row << 7) + (ka << 1); off ^= (row & 7) << 4;
          afr[mt] = *(const bf16x8*)(smem + M_P + off);
        }
        bf16x8 bfr[2];
        #pragma unroll
        for (int nt = 0; nt < 2; ++nt) {
          int d = wvid * 32 + nt * 16 + l15;
          int off = (d << 7) + (ka << 1); off ^= (d & 7) << 4;
          bfr[nt] = *(const bf16x8*)(smem + M_KV + off);
        }
        #pragma unroll
        for (int mt = 0; mt < 4; ++mt)
          #pragma unroll
          for (int nt = 0; nt < 2; ++nt)
            pacc[mt][nt] = __builtin_amdgcn_mfma_f32_16x16x32_bf16(afr[mt], bfr[nt], pacc[mt][nt], 0, 0, 0);
      }
      #pragma unroll
      for (int nt = 0; nt < 2; ++nt) {
        int d = wvid * 32 + nt * 16 + l15;
        #pragma unroll
        for (int mt = 0; mt < 4; ++mt)
          #pragma unroll
          for (int rg = 0; rg < 4; ++rg) {
            int row = mt * 16 + rbase + rg;
            int off = (row << 8) + (d << 1); off ^= (row & 7) << 4;
            *(unsigned short*)(ab + off) = f2b(pacc[mt][nt][rg]);
          }
      }
    }
    __syncthreads();
  }

  const unsigned short* wo = wqkvo + 3 * 262144;
  for (int half = 0; half < 2; ++half) {
    f32x4 oacc[4][4];
    #pragma unroll
    for (int mt = 0; mt < 4; ++mt)
      #pragma unroll
      for (int nt = 0; nt < 4; ++nt) oacc[mt][nt] = (f32x4){0.f, 0.f, 0.f, 0.f};
    for (int kk = 0; kk < 512; kk += 32) {
      const char* abk = smem + M_AB + (kk >> 7) * 16384;
      int ka = (kk & 127) + kl;
      bf16x8 afr[4];
      #pragma unroll
      for (int mt = 0; mt < 4; ++mt) {
        int row = mt * 16 + l15;
        int off = (row << 8) + (ka << 1); off ^= (row & 7) << 4;
        afr[mt] = *(const bf16x8*)(abk + off);
      }
      bf16x8 bfr[4];
      #pragma unroll
      for (int nt = 0; nt < 4; ++nt) {
        int j = wvid * 128 + half * 64 + nt * 16 + l15;
        bfr[nt] = *(const bf16x8*)(wo + (size_t)j * 512 + kk + kl);
      }
      #pragma unroll
      for (int mt = 0; mt < 4; ++mt)
        #pragma unroll
        for (int nt = 0; nt < 4; ++nt)
          oacc[mt][nt] = __builtin_amdgcn_mfma_f32_16x16x32_bf16(afr[mt], bfr[nt], oacc[mt][nt], 0, 0, 0);
    }
    #pragma unroll
    for (int mt = 0; mt < 4; ++mt) {
      #pragma unroll
      for (int rg = 0; rg < 4; ++rg) {
        int r = mt * 16 + rbase + rg;
        int gy = wy * 8 + (r >> 3), gx = wx * 8 + (r & 7);
        if (gy < Ht && gx < Wt) {
          float* po = out + ((size_t)b * NTOK + gy * Wt + gx) * C;
          #pragma unroll
          for (int nt = 0; nt < 4; ++nt) {
            int j = wvid * 128 + half * 64 + nt * 16 + l15;
            po[j] = oacc[mt][nt][rg] + bo[j];
          }
        }
      }
    }
  }
}

extern "C" void kernel_launch(void* const* d_in, const int* in_sizes, int n_in,
                              void* d_out, int out_size, void* d_ws, size_t ws_size,
                              hipStream_t stream) {
  const float* x  = (const float*)d_in[0];
  const float* Wq = (const float*)d_in[2];
  const float* bq = (const float*)d_in[3];
  const float* Wk = (const float*)d_in[4];
  const float* bk = (const float*)d_in[5];
  const float* Wv = (const float*)d_in[6];
  const float* bv = (const float*)d_in[7];
  const float* Wo = (const float*)d_in[8];
  const float* bo = (const float*)d_in[9];
  unsigned short* wbf = (unsigned short*)d_ws;

  cvt_weights<<<1024, 256, 0, stream>>>(Wq, Wk, Wv, Wo, wbf);

  const size_t need = (WOFF + SLABE) * 2;   // 2 MB weights + 117 MB attn slab
  if (ws_size < need) {
    hipFuncSetAttribute((const void*)swmhsa_mono,
                        hipFuncAttributeMaxDynamicSharedMemorySize, M_LDS);
    swmhsa_mono<<<NBLK, 256, M_LDS, stream>>>(x, wbf, bq, bk, bv, bo, (float*)d_out);
    return;
  }

  unsigned short* slab = wbf + WOFF;
  qkv_attn<<<NBLK, 256, 0, stream>>>(x, wbf, bq, bk, bv, slab);
  proj_o<<<NBLK, 256, 0, stream>>>(slab, wbf + 3 * 262144, bo, (float*)d_out);
}

// Round 9
// 753.529 us; speedup vs baseline: 1.1279x; 1.1279x over previous
//
#include <hip/hip_runtime.h>
#include <hip/hip_bf16.h>

using bf16x8 = __attribute__((ext_vector_type(8))) short;
using f32x4  = __attribute__((ext_vector_type(4))) float;
using u16x4  = __attribute__((ext_vector_type(4))) unsigned short;

constexpr int Ht = 60, Wt = 108, C = 512;
constexpr int GWt = 14, NWIN = 112, NTOK = Ht * Wt, BT = 16;
constexpr int NBLK = BT * NWIN;                   // 1792 window blocks
constexpr float SCALE = 0.08838834764831845f;     // 1/sqrt(128)
constexpr size_t WOFF = 4 * 262144;               // weights: 4x512x512 bf16 elems
constexpr size_t SLABE = (size_t)NBLK * 64 * 512; // one slab: elems (bf16)

__device__ __forceinline__ unsigned short f2b(float f) {   // f32 -> bf16 RNE
  union { float f; unsigned u; } v; v.f = f;
  unsigned r = v.u + 0x7fffu + ((v.u >> 16) & 1u);
  return (unsigned short)(r >> 16);
}

__global__ void cvt_weights(const float* __restrict__ a, const float* __restrict__ b,
                            const float* __restrict__ c, const float* __restrict__ d,
                            unsigned short* __restrict__ dst) {
  int i = blockIdx.x * blockDim.x + threadIdx.x;   // 262144 threads, 4 f32 each
  int m  = i >> 16;
  int o4 = i & 65535;
  const float* src = (m == 0) ? a : (m == 1) ? b : (m == 2) ? c : d;
  float4 v = *(const float4*)(src + (size_t)o4 * 4);
  u16x4 o;
  o[0] = f2b(v.x); o[1] = f2b(v.y); o[2] = f2b(v.z); o[3] = f2b(v.w);
  *(u16x4*)(dst + (size_t)m * 262144 + (size_t)o4 * 4) = o;
}

// ============ TIER 1, K1: window-tiled QKV GEMM -> 3 bf16 slabs =============
// Barrier-free after staging: 3 matrices x 2 halves, acc[4][4] each.
extern "C" __global__ __launch_bounds__(256, 1)
void qkv_gemm(const float* __restrict__ x,
              const unsigned short* __restrict__ wbf,   // [4][512][512] bf16
              const float* __restrict__ bq, const float* __restrict__ bk,
              const float* __restrict__ bv,
              unsigned short* __restrict__ qs,
              unsigned short* __restrict__ ks,
              unsigned short* __restrict__ vs)
{
  __shared__ char smem[65536];                // x window [64][512] bf16, swizzled
  const int tid   = threadIdx.x;
  const int wvid  = tid >> 6;
  const int lane  = tid & 63;
  const int l15   = lane & 15;
  const int kl    = (lane >> 4) << 3;
  const int rbase = (lane >> 4) << 2;

  const int blk = blockIdx.x;
  const int b   = blk / NWIN;
  const int w   = blk - b * NWIN;
  const int wy  = w / GWt, wx = w - wy * GWt;

  // stage window tokens: f32 -> bf16, swizzled; padded tokens = 0
  for (int it = 0; it < 32; ++it) {
    int f  = it * 256 + tid;
    int r  = f >> 7;
    int c4 = f & 127;
    int gy = wy * 8 + (r >> 3), gx = wx * 8 + (r & 7);
    float4 v = make_float4(0.f, 0.f, 0.f, 0.f);
    if (gy < Ht && gx < Wt)
      v = *(const float4*)(x + ((size_t)b * NTOK + gy * Wt + gx) * C + c4 * 4);
    u16x4 o;
    o[0] = f2b(v.x); o[1] = f2b(v.y); o[2] = f2b(v.z); o[3] = f2b(v.w);
    int off = (r << 10) + (c4 << 3);
    off ^= (r & 7) << 4;
    *(u16x4*)(smem + off) = o;
  }
  __syncthreads();

  for (int m = 0; m < 3; ++m) {
    const unsigned short* wm = wbf + (size_t)m * 262144;
    const float* bias = (m == 0) ? bq : (m == 1) ? bk : bv;
    unsigned short* dst = ((m == 0) ? qs : (m == 1) ? ks : vs) + (size_t)blk * 32768;
    for (int half = 0; half < 2; ++half) {
      f32x4 acc[4][4];
      #pragma unroll
      for (int mt = 0; mt < 4; ++mt)
        #pragma unroll
        for (int nt = 0; nt < 4; ++nt) acc[mt][nt] = (f32x4){0.f, 0.f, 0.f, 0.f};
      #pragma unroll 4
      for (int kk = 0; kk < 512; kk += 32) {
        int ka = kk + kl;
        bf16x8 afr[4];
        #pragma unroll
        for (int mt = 0; mt < 4; ++mt) {
          int row = mt * 16 + l15;
          int off = (row << 10) + (ka << 1); off ^= (row & 7) << 4;
          afr[mt] = *(const bf16x8*)(smem + off);
        }
        bf16x8 bfr[4];
        #pragma unroll
        for (int nt = 0; nt < 4; ++nt) {
          int j = wvid * 128 + half * 64 + nt * 16 + l15;
          bfr[nt] = *(const bf16x8*)(wm + (size_t)j * 512 + ka);
        }
        #pragma unroll
        for (int mt = 0; mt < 4; ++mt)
          #pragma unroll
          for (int nt = 0; nt < 4; ++nt)
            acc[mt][nt] = __builtin_amdgcn_mfma_f32_16x16x32_bf16(afr[mt], bfr[nt], acc[mt][nt], 0, 0, 0);
      }
      #pragma unroll
      for (int nt = 0; nt < 4; ++nt) {
        int j = wvid * 128 + half * 64 + nt * 16 + l15;
        float bi = bias[j];
        #pragma unroll
        for (int mt = 0; mt < 4; ++mt)
          #pragma unroll
          for (int rg = 0; rg < 4; ++rg) {
            int row = mt * 16 + rbase + rg;
            dst[row * 512 + j] = f2b(acc[mt][nt][rg] + bi);
          }
      }
    }
  }
}

// ============ TIER 1, K2: per-(window,head) attention ========================
// LDS 40KB: K [64][128] swz 16K | Vt [128][64] swz 16K | P [64][64] swz 8K
// attn output aliases the Q slab slice this block consumed (race-free).
extern "C" __global__ __launch_bounds__(256, 4)
void attn2(unsigned short* __restrict__ qs,           // in: Q; out: attn (alias)
           const unsigned short* __restrict__ ks,
           const unsigned short* __restrict__ vs)
{
  __shared__ char kbuf[16384];
  __shared__ char vtb[16384];
  __shared__ char pbf[8192];

  const int tid   = threadIdx.x;
  const int wvid  = tid >> 6;
  const int lane  = tid & 63;
  const int l15   = lane & 15;
  const int kl    = (lane >> 4) << 3;
  const int rbase = (lane >> 4) << 2;

  const int w = blockIdx.x;
  const int h = blockIdx.y;
  unsigned short*       Qs = qs + (size_t)w * 32768 + h * 128;
  const unsigned short* Ks = ks + (size_t)w * 32768 + h * 128;
  const unsigned short* Vs = vs + (size_t)w * 32768 + h * 128;

  // stage K [64][128] -> LDS swizzled (coalesced 16B chunks)
  #pragma unroll
  for (int it = 0; it < 4; ++it) {
    int f  = it * 256 + tid;       // u16x8 chunk; 16 per row
    int r  = f >> 4;
    int c8 = f & 15;
    bf16x8 v = *(const bf16x8*)(Ks + r * 512 + c8 * 8);
    int off = (r << 8) + (c8 << 4); off ^= (r & 7) << 4;
    *(bf16x8*)(kbuf + off) = v;
  }
  // stage V transposed: thread (tok = tid&63, dg = tid>>6) reads 32 d's of
  // its token (64B contiguous), writes Vt[d][tok] (concurrent lanes span banks)
  {
    int tok = tid & 63;
    int dg  = tid >> 6;            // 0..3 -> d = dg*32 .. +31
    bf16x8 vv[4];
    #pragma unroll
    for (int s = 0; s < 4; ++s)
      vv[s] = *(const bf16x8*)(Vs + tok * 512 + dg * 32 + s * 8);
    #pragma unroll
    for (int s = 0; s < 4; ++s)
      #pragma unroll
      for (int e = 0; e < 8; ++e) {
        int d = dg * 32 + s * 8 + e;
        int off = (d << 7) + (tok << 1); off ^= (d & 7) << 4;
        *(unsigned short*)(vtb + off) = (unsigned short)vv[s][e];
      }
  }
  __syncthreads();

  // QK^T: wave owns 16 q-rows; Q read straight from slab
  f32x4 sacc[4];
  #pragma unroll
  for (int nt = 0; nt < 4; ++nt) sacc[nt] = (f32x4){0.f, 0.f, 0.f, 0.f};
  #pragma unroll
  for (int kk = 0; kk < 128; kk += 32) {
    int ka = kk + kl;
    bf16x8 afr = *(const bf16x8*)(Qs + (wvid * 16 + l15) * 512 + ka);
    #pragma unroll
    for (int nt = 0; nt < 4; ++nt) {
      int jr = nt * 16 + l15;
      int o2 = (jr << 8) + (ka << 1); o2 ^= (jr & 7) << 4;
      bf16x8 bfr = *(const bf16x8*)(kbuf + o2);
      sacc[nt] = __builtin_amdgcn_mfma_f32_16x16x32_bf16(afr, bfr, sacc[nt], 0, 0, 0);
    }
  }
  // softmax (each row lives in one 16-lane group), P -> LDS
  #pragma unroll
  for (int rg = 0; rg < 4; ++rg) {
    float m = -3.0e38f;
    #pragma unroll
    for (int nt = 0; nt < 4; ++nt) m = fmaxf(m, sacc[nt][rg]);
    #pragma unroll
    for (int dd = 1; dd < 16; dd <<= 1) m = fmaxf(m, __shfl_xor(m, dd, 64));
    float s = 0.f, e[4];
    #pragma unroll
    for (int nt = 0; nt < 4; ++nt) { e[nt] = __expf((sacc[nt][rg] - m) * SCALE); s += e[nt]; }
    #pragma unroll
    for (int dd = 1; dd < 16; dd <<= 1) s += __shfl_xor(s, dd, 64);
    float inv = 1.f / s;
    int row = wvid * 16 + rbase + rg;
    #pragma unroll
    for (int nt = 0; nt < 4; ++nt) {
      int col = nt * 16 + l15;
      int off = (row << 7) + (col << 1); off ^= (row & 7) << 4;
      *(unsigned short*)(pbf + off) = f2b(e[nt] * inv);
    }
  }
  __syncthreads();

  // PV: all 64 rows x wave's 32 d-cols, K=64
  f32x4 pacc[4][2];
  #pragma unroll
  for (int mt = 0; mt < 4; ++mt)
    #pragma unroll
    for (int nt = 0; nt < 2; ++nt) pacc[mt][nt] = (f32x4){0.f, 0.f, 0.f, 0.f};
  #pragma unroll
  for (int kk = 0; kk < 64; kk += 32) {
    int ka = kk + kl;
    bf16x8 afr[4];
    #pragma unroll
    for (int mt = 0; mt < 4; ++mt) {
      int row = mt * 16 + l15;
      int off = (row << 7) + (ka << 1); off ^= (row & 7) << 4;
      afr[mt] = *(const bf16x8*)(pbf + off);
    }
    bf16x8 bfr[2];
    #pragma unroll
    for (int nt = 0; nt < 2; ++nt) {
      int d = wvid * 32 + nt * 16 + l15;
      int off = (d << 7) + (ka << 1); off ^= (d & 7) << 4;
      bfr[nt] = *(const bf16x8*)(vtb + off);
    }
    #pragma unroll
    for (int mt = 0; mt < 4; ++mt)
      #pragma unroll
      for (int nt = 0; nt < 2; ++nt)
        pacc[mt][nt] = __builtin_amdgcn_mfma_f32_16x16x32_bf16(afr[mt], bfr[nt], pacc[mt][nt], 0, 0, 0);
  }
  // write attn over the Q slice (this block is its only reader)
  #pragma unroll
  for (int nt = 0; nt < 2; ++nt) {
    int d = wvid * 32 + nt * 16 + l15;
    #pragma unroll
    for (int mt = 0; mt < 4; ++mt)
      #pragma unroll
      for (int rg = 0; rg < 4; ++rg) {
        int row = mt * 16 + rbase + rg;
        Qs[row * 512 + d] = f2b(pacc[mt][nt][rg]);
      }
  }
}

// ============ K3: out = slab @ Wo^T + bo (window-ordered slab) ==============
extern "C" __global__ __launch_bounds__(256, 1)
void proj_o(const unsigned short* __restrict__ slab,
            const unsigned short* __restrict__ wo,
            const float* __restrict__ bo,
            float* __restrict__ out)
{
  __shared__ char smem[65536];                 // [64][512] bf16, swizzled
  const int tid   = threadIdx.x;
  const int wvid  = tid >> 6;
  const int lane  = tid & 63;
  const int l15   = lane & 15;
  const int kl    = (lane >> 4) << 3;
  const int rbase = (lane >> 4) << 2;

  const int blk = blockIdx.x;
  const int b   = blk / NWIN;
  const int w   = blk - b * NWIN;
  const int wy  = w / GWt, wx = w - wy * GWt;

  const unsigned short* src = slab + (size_t)blk * 32768;
  for (int it = 0; it < 16; ++it) {
    int f  = it * 256 + tid;                   // u16x8 group; 64 per row
    int r  = f >> 6;
    int c8 = f & 63;
    bf16x8 v = *(const bf16x8*)(src + r * 512 + c8 * 8);
    int off = (r << 10) + (c8 << 4);
    off ^= (r & 7) << 4;
    *(bf16x8*)(smem + off) = v;
  }
  __syncthreads();

  for (int half = 0; half < 2; ++half) {
    f32x4 acc[4][4];
    #pragma unroll
    for (int mt = 0; mt < 4; ++mt)
      #pragma unroll
      for (int nt = 0; nt < 4; ++nt) acc[mt][nt] = (f32x4){0.f, 0.f, 0.f, 0.f};
    #pragma unroll 2
    for (int kk = 0; kk < 512; kk += 32) {
      int ka = kk + kl;
      bf16x8 afr[4];
      #pragma unroll
      for (int mt = 0; mt < 4; ++mt) {
        int row = mt * 16 + l15;
        int off = (row << 10) + (ka << 1); off ^= (row & 7) << 4;
        afr[mt] = *(const bf16x8*)(smem + off);
      }
      bf16x8 bfr[4];
      #pragma unroll
      for (int nt = 0; nt < 4; ++nt) {
        int j = wvid * 128 + half * 64 + nt * 16 + l15;
        bfr[nt] = *(const bf16x8*)(wo + (size_t)j * 512 + ka);
      }
      #pragma unroll
      for (int mt = 0; mt < 4; ++mt)
        #pragma unroll
        for (int nt = 0; nt < 4; ++nt)
          acc[mt][nt] = __builtin_amdgcn_mfma_f32_16x16x32_bf16(afr[mt], bfr[nt], acc[mt][nt], 0, 0, 0);
    }
    #pragma unroll
    for (int mt = 0; mt < 4; ++mt)
      #pragma unroll
      for (int rg = 0; rg < 4; ++rg) {
        int r = mt * 16 + rbase + rg;
        int gy = wy * 8 + (r >> 3), gx = wx * 8 + (r & 7);
        if (gy < Ht && gx < Wt) {
          float* po = out + ((size_t)b * NTOK + gy * Wt + gx) * C;
          #pragma unroll
          for (int nt = 0; nt < 4; ++nt) {
            int j = wvid * 128 + half * 64 + nt * 16 + l15;
            po[j] = acc[mt][nt][rg] + bo[j];
          }
        }
      }
  }
}

// ============ TIER 2: round-7 fused per-window kernel (proven, 119MB ws) ====
extern "C" __global__ __launch_bounds__(256, 1)
void qkv_attn(const float* __restrict__ x,
              const unsigned short* __restrict__ wbf,
              const float* __restrict__ bq, const float* __restrict__ bk,
              const float* __restrict__ bv,
              unsigned short* __restrict__ slab)
{
  __shared__ char smem[73728];
  char* qb = smem + 32768;
  char* kb = smem + 49152;
  char* pb = smem + 65536;

  const int tid   = threadIdx.x;
  const int wvid  = tid >> 6;
  const int lane  = tid & 63;
  const int l15   = lane & 15;
  const int kl    = (lane >> 4) << 3;
  const int rbase = (lane >> 4) << 2;

  const int blk = blockIdx.x;
  const int b   = blk / NWIN;
  const int w   = blk - b * NWIN;
  const int wy  = w / GWt, wx = w - wy * GWt;

  for (int it = 0; it < 32; ++it) {
    int f  = it * 256 + tid;
    int r  = f >> 7;
    int c4 = f & 127;
    int gy = wy * 8 + (r >> 3), gx = wx * 8 + (r & 7);
    float4 v = make_float4(0.f, 0.f, 0.f, 0.f);
    if (gy < Ht && gx < Wt)
      v = *(const float4*)(x + ((size_t)b * NTOK + gy * Wt + gx) * C + c4 * 4);
    u16x4 o;
    o[0] = f2b(v.x); o[1] = f2b(v.y); o[2] = f2b(v.z); o[3] = f2b(v.w);
    int lc  = c4 & 63;
    int off = (r << 9) + (lc << 3);
    off ^= (r & 7) << 4;
    off += (c4 >> 6) * 32768;
    *(u16x4*)(smem + off) = o;
  }
  __syncthreads();

  bf16x8 xr[4][8];
  #pragma unroll
  for (int mt = 0; mt < 4; ++mt) {
    int row = mt * 16 + l15;
    #pragma unroll
    for (int s = 0; s < 8; ++s) {
      int off = (row << 9) + ((s * 32 + kl) << 1);
      off ^= (row & 7) << 4;
      xr[mt][s] = *(const bf16x8*)(smem + 32768 + off);
    }
  }
  __syncthreads();

  auto gemm_r = [&](const unsigned short* wm, int h, f32x4 (&acc)[4][2]) {
    #pragma unroll
    for (int mt = 0; mt < 4; ++mt)
      #pragma unroll
      for (int nt = 0; nt < 2; ++nt) acc[mt][nt] = (f32x4){0.f, 0.f, 0.f, 0.f};
    #pragma unroll
    for (int s = 0; s < 16; ++s) {
      int ka = s * 32 + kl;
      bf16x8 afr[4];
      if (s < 8) {
        #pragma unroll
        for (int mt = 0; mt < 4; ++mt) {
          int row = mt * 16 + l15;
          int off = (row << 9) + (ka << 1);
          off ^= (row & 7) << 4;
          afr[mt] = *(const bf16x8*)(smem + off);
        }
      } else {
        #pragma unroll
        for (int mt = 0; mt < 4; ++mt) afr[mt] = xr[mt][s - 8];
      }
      bf16x8 bfr[2];
      #pragma unroll
      for (int nt = 0; nt < 2; ++nt) {
        int jg = h * 128 + wvid * 32 + nt * 16 + l15;
        bfr[nt] = *(const bf16x8*)(wm + (size_t)jg * 512 + ka);
      }
      #pragma unroll
      for (int mt = 0; mt < 4; ++mt)
        #pragma unroll
        for (int nt = 0; nt < 2; ++nt)
          acc[mt][nt] = __builtin_amdgcn_mfma_f32_16x16x32_bf16(afr[mt], bfr[nt], acc[mt][nt], 0, 0, 0);
    }
  };

  auto store_rm = [&](f32x4 (&acc)[4][2], char* base, const float* bias, int h) {
    #pragma unroll
    for (int nt = 0; nt < 2; ++nt) {
      int col = wvid * 32 + nt * 16 + l15;
      float bi = bias[h * 128 + col];
      #pragma unroll
      for (int mt = 0; mt < 4; ++mt)
        #pragma unroll
        for (int rg = 0; rg < 4; ++rg) {
          int row = mt * 16 + rbase + rg;
          int off = (row << 8) + (col << 1);
          off ^= (row & 7) << 4;
          *(unsigned short*)(base + off) = f2b(acc[mt][nt][rg] + bi);
        }
    }
  };

  unsigned short* sl = slab + (size_t)blk * 32768;

  for (int h = 0; h < 4; ++h) {
    {
      f32x4 acc[4][2];
      gemm_r(wbf + 0 * 262144, h, acc);
      store_rm(acc, qb, bq, h);
      gemm_r(wbf + 1 * 262144, h, acc);
      store_rm(acc, kb, bk, h);
    }
    __syncthreads();
    f32x4 vacc[4][2];
    {
      f32x4 sacc[4];
      #pragma unroll
      for (int nt = 0; nt < 4; ++nt) sacc[nt] = (f32x4){0.f, 0.f, 0.f, 0.f};
      #pragma unroll
      for (int kk = 0; kk < 128; kk += 32) {
        int ka = kk + kl;
        int row = wvid * 16 + l15;
        int off = (row << 8) + (ka << 1); off ^= (row & 7) << 4;
        bf16x8 afr = *(const bf16x8*)(qb + off);
        #pragma unroll
        for (int nt = 0; nt < 4; ++nt) {
          int jr = nt * 16 + l15;
          int o2 = (jr << 8) + (ka << 1); o2 ^= (jr & 7) << 4;
          bf16x8 bfr = *(const bf16x8*)(kb + o2);
          sacc[nt] = __builtin_amdgcn_mfma_f32_16x16x32_bf16(afr, bfr, sacc[nt], 0, 0, 0);
        }
      }
      #pragma unroll
      for (int rg = 0; rg < 4; ++rg) {
        float m = -3.0e38f;
        #pragma unroll
        for (int nt = 0; nt < 4; ++nt) m = fmaxf(m, sacc[nt][rg]);
        #pragma unroll
        for (int dd = 1; dd < 16; dd <<= 1) m = fmaxf(m, __shfl_xor(m, dd, 64));
        float s = 0.f, e[4];
        #pragma unroll
        for (int nt = 0; nt < 4; ++nt) { e[nt] = __expf((sacc[nt][rg] - m) * SCALE); s += e[nt]; }
        #pragma unroll
        for (int dd = 1; dd < 16; dd <<= 1) s += __shfl_xor(s, dd, 64);
        float inv = 1.f / s;
        int row = wvid * 16 + rbase + rg;
        #pragma unroll
        for (int nt = 0; nt < 4; ++nt) {
          int col = nt * 16 + l15;
          int off = (row << 7) + (col << 1); off ^= (row & 7) << 4;
          *(unsigned short*)(pb + off) = f2b(e[nt] * inv);
        }
      }
      gemm_r(wbf + 2 * 262144, h, vacc);
    }
    __syncthreads();
    {
      #pragma unroll
      for (int nt = 0; nt < 2; ++nt) {
        int d = wvid * 32 + nt * 16 + l15;
        float bi = bv[h * 128 + d];
        #pragma unroll
        for (int mt = 0; mt < 4; ++mt) {
          int j0 = mt * 16 + rbase;
          u16x4 pk;
          #pragma unroll
          for (int rg = 0; rg < 4; ++rg) pk[rg] = f2b(vacc[mt][nt][rg] + bi);
          int off = (d << 7) + (j0 << 1); off ^= (d & 7) << 4;
          *(u16x4*)(kb + off) = pk;
        }
      }
    }
    __syncthreads();
    {
      f32x4 pacc[4][2];
      #pragma unroll
      for (int mt = 0; mt < 4; ++mt)
        #pragma unroll
        for (int nt = 0; nt < 2; ++nt) pacc[mt][nt] = (f32x4){0.f, 0.f, 0.f, 0.f};
      #pragma unroll
      for (int kk = 0; kk < 64; kk += 32) {
        int ka = kk + kl;
        bf16x8 afr[4];
        #pragma unroll
        for (int mt = 0; mt < 4; ++mt) {
          int row = mt * 16 + l15;
          int off = (row << 7) + (ka << 1); off ^= (row & 7) << 4;
          afr[mt] = *(const bf16x8*)(pb + off);
        }
        bf16x8 bfr[2];
        #pragma unroll
        for (int nt = 0; nt < 2; ++nt) {
          int d = wvid * 32 + nt * 16 + l15;
          int off = (d << 7) + (ka << 1); off ^= (d & 7) << 4;
          bfr[nt] = *(const bf16x8*)(kb + off);
        }
        #pragma unroll
        for (int mt = 0; mt < 4; ++mt)
          #pragma unroll
          for (int nt = 0; nt < 2; ++nt)
            pacc[mt][nt] = __builtin_amdgcn_mfma_f32_16x16x32_bf16(afr[mt], bfr[nt], pacc[mt][nt], 0, 0, 0);
      }
      #pragma unroll
      for (int nt = 0; nt < 2; ++nt) {
        int d = wvid * 32 + nt * 16 + l15;
        #pragma unroll
        for (int mt = 0; mt < 4; ++mt)
          #pragma unroll
          for (int rg = 0; rg < 4; ++rg) {
            int row = mt * 16 + rbase + rg;
            sl[row * 512 + h * 128 + d] = f2b(pacc[mt][nt][rg]);
          }
      }
    }
    __syncthreads();
  }
}

extern "C" void kernel_launch(void* const* d_in, const int* in_sizes, int n_in,
                              void* d_out, int out_size, void* d_ws, size_t ws_size,
                              hipStream_t stream) {
  const float* x  = (const float*)d_in[0];
  const float* Wq = (const float*)d_in[2];
  const float* bq = (const float*)d_in[3];
  const float* Wk = (const float*)d_in[4];
  const float* bk = (const float*)d_in[5];
  const float* Wv = (const float*)d_in[6];
  const float* bv = (const float*)d_in[7];
  const float* Wo = (const float*)d_in[8];
  const float* bo = (const float*)d_in[9];
  unsigned short* wbf = (unsigned short*)d_ws;

  cvt_weights<<<1024, 256, 0, stream>>>(Wq, Wk, Wv, Wo, wbf);

  const size_t need_full = (WOFF + 3 * SLABE) * 2;  // ~354 MB
  const size_t need_r7   = (WOFF + SLABE) * 2;      // ~119 MB

  if (ws_size >= need_full) {
    unsigned short* qs = wbf + WOFF;
    unsigned short* ks = qs + SLABE;
    unsigned short* vs = ks + SLABE;
    qkv_gemm<<<NBLK, 256, 0, stream>>>(x, wbf, bq, bk, bv, qs, ks, vs);
    attn2<<<dim3(NBLK, 4), 256, 0, stream>>>(qs, ks, vs);
    proj_o<<<NBLK, 256, 0, stream>>>(qs, wbf + 3 * 262144, bo, (float*)d_out);
  } else {
    // tier 2: proven round-7 path (works from 119 MB ws)
    unsigned short* slab = wbf + WOFF;
    qkv_attn<<<NBLK, 256, 0, stream>>>(x, wbf, bq, bk, bv, slab);
    proj_o<<<NBLK, 256, 0, stream>>>(slab, wbf + 3 * 262144, bo, (float*)d_out);
  }
}

// Round 10
// 707.752 us; speedup vs baseline: 1.2009x; 1.0647x over previous
//
#include <hip/hip_runtime.h>
#include <hip/hip_bf16.h>

using bf16x8 = __attribute__((ext_vector_type(8))) short;
using f32x4  = __attribute__((ext_vector_type(4))) float;
using u16x4  = __attribute__((ext_vector_type(4))) unsigned short;

constexpr int Ht = 60, Wt = 108, C = 512;
constexpr int GWt = 14, NWIN = 112, NTOK = Ht * Wt, BT = 16;
constexpr int NBLK = BT * NWIN;                   // 1792 window blocks
constexpr float SCALE = 0.08838834764831845f;     // 1/sqrt(128)
constexpr size_t WOFF = 4 * 262144;               // weights: 4x512x512 bf16 elems
constexpr size_t SLABE = (size_t)NBLK * 64 * 512; // one slab: elems (bf16)

__device__ __forceinline__ unsigned short f2b(float f) {   // f32 -> bf16 RNE
  union { float f; unsigned u; } v; v.f = f;
  unsigned r = v.u + 0x7fffu + ((v.u >> 16) & 1u);
  return (unsigned short)(r >> 16);
}

__global__ void cvt_weights(const float* __restrict__ a, const float* __restrict__ b,
                            const float* __restrict__ c, const float* __restrict__ d,
                            unsigned short* __restrict__ dst) {
  int i = blockIdx.x * blockDim.x + threadIdx.x;   // 262144 threads, 4 f32 each
  int m  = i >> 16;
  int o4 = i & 65535;
  const float* src = (m == 0) ? a : (m == 1) ? b : (m == 2) ? c : d;
  float4 v = *(const float4*)(src + (size_t)o4 * 4);
  u16x4 o;
  o[0] = f2b(v.x); o[1] = f2b(v.y); o[2] = f2b(v.z); o[3] = f2b(v.w);
  *(u16x4*)(dst + (size_t)m * 262144 + (size_t)o4 * 4) = o;
}

// ============ TIER 1, K1: window-tiled QKV GEMM -> 3 bf16 slabs =============
// Barrier-free after staging: 3 matrices x 2 halves, acc[4][4] each.
// (256,2): force unified VGPR+AGPR <= 256/wave -> 2 waves/SIMD residency.
extern "C" __global__ __launch_bounds__(256, 2)
void qkv_gemm(const float* __restrict__ x,
              const unsigned short* __restrict__ wbf,   // [4][512][512] bf16
              const float* __restrict__ bq, const float* __restrict__ bk,
              const float* __restrict__ bv,
              unsigned short* __restrict__ qs,
              unsigned short* __restrict__ ks,
              unsigned short* __restrict__ vs)
{
  __shared__ char smem[65536];                // x window [64][512] bf16, swizzled
  const int tid   = threadIdx.x;
  const int wvid  = tid >> 6;
  const int lane  = tid & 63;
  const int l15   = lane & 15;
  const int kl    = (lane >> 4) << 3;
  const int rbase = (lane >> 4) << 2;

  const int blk = blockIdx.x;
  const int b   = blk / NWIN;
  const int w   = blk - b * NWIN;
  const int wy  = w / GWt, wx = w - wy * GWt;

  // stage window tokens: f32 -> bf16, swizzled; padded tokens = 0
  for (int it = 0; it < 32; ++it) {
    int f  = it * 256 + tid;
    int r  = f >> 7;
    int c4 = f & 127;
    int gy = wy * 8 + (r >> 3), gx = wx * 8 + (r & 7);
    float4 v = make_float4(0.f, 0.f, 0.f, 0.f);
    if (gy < Ht && gx < Wt)
      v = *(const float4*)(x + ((size_t)b * NTOK + gy * Wt + gx) * C + c4 * 4);
    u16x4 o;
    o[0] = f2b(v.x); o[1] = f2b(v.y); o[2] = f2b(v.z); o[3] = f2b(v.w);
    int off = (r << 10) + (c4 << 3);
    off ^= (r & 7) << 4;
    *(u16x4*)(smem + off) = o;
  }
  __syncthreads();

  for (int m = 0; m < 3; ++m) {
    const unsigned short* wm = wbf + (size_t)m * 262144;
    const float* bias = (m == 0) ? bq : (m == 1) ? bk : bv;
    unsigned short* dst = ((m == 0) ? qs : (m == 1) ? ks : vs) + (size_t)blk * 32768;
    for (int half = 0; half < 2; ++half) {
      f32x4 acc[4][4];
      #pragma unroll
      for (int mt = 0; mt < 4; ++mt)
        #pragma unroll
        for (int nt = 0; nt < 4; ++nt) acc[mt][nt] = (f32x4){0.f, 0.f, 0.f, 0.f};
      #pragma unroll 4
      for (int kk = 0; kk < 512; kk += 32) {
        int ka = kk + kl;
        bf16x8 afr[4];
        #pragma unroll
        for (int mt = 0; mt < 4; ++mt) {
          int row = mt * 16 + l15;
          int off = (row << 10) + (ka << 1); off ^= (row & 7) << 4;
          afr[mt] = *(const bf16x8*)(smem + off);
        }
        bf16x8 bfr[4];
        #pragma unroll
        for (int nt = 0; nt < 4; ++nt) {
          int j = wvid * 128 + half * 64 + nt * 16 + l15;
          bfr[nt] = *(const bf16x8*)(wm + (size_t)j * 512 + ka);
        }
        #pragma unroll
        for (int mt = 0; mt < 4; ++mt)
          #pragma unroll
          for (int nt = 0; nt < 4; ++nt)
            acc[mt][nt] = __builtin_amdgcn_mfma_f32_16x16x32_bf16(afr[mt], bfr[nt], acc[mt][nt], 0, 0, 0);
      }
      #pragma unroll
      for (int nt = 0; nt < 4; ++nt) {
        int j = wvid * 128 + half * 64 + nt * 16 + l15;
        float bi = bias[j];
        #pragma unroll
        for (int mt = 0; mt < 4; ++mt)
          #pragma unroll
          for (int rg = 0; rg < 4; ++rg) {
            int row = mt * 16 + rbase + rg;
            dst[row * 512 + j] = f2b(acc[mt][nt][rg] + bi);
          }
      }
    }
  }
}

// ============ TIER 1, K2: per-(window,head) attention ========================
// LDS 40KB: K [64][128] swz 16K | Vt [128][64] swz 16K | P [64][64] swz 8K
// attn output aliases the Q slab slice this block consumed (race-free).
extern "C" __global__ __launch_bounds__(256, 4)
void attn2(unsigned short* __restrict__ qs,           // in: Q; out: attn (alias)
           const unsigned short* __restrict__ ks,
           const unsigned short* __restrict__ vs)
{
  __shared__ char kbuf[16384];
  __shared__ char vtb[16384];
  __shared__ char pbf[8192];

  const int tid   = threadIdx.x;
  const int wvid  = tid >> 6;
  const int lane  = tid & 63;
  const int l15   = lane & 15;
  const int kl    = (lane >> 4) << 3;
  const int rbase = (lane >> 4) << 2;

  const int w = blockIdx.x;
  const int h = blockIdx.y;
  unsigned short*       Qs = qs + (size_t)w * 32768 + h * 128;
  const unsigned short* Ks = ks + (size_t)w * 32768 + h * 128;
  const unsigned short* Vs = vs + (size_t)w * 32768 + h * 128;

  // stage K [64][128] -> LDS swizzled (coalesced 16B chunks)
  #pragma unroll
  for (int it = 0; it < 4; ++it) {
    int f  = it * 256 + tid;       // u16x8 chunk; 16 per row
    int r  = f >> 4;
    int c8 = f & 15;
    bf16x8 v = *(const bf16x8*)(Ks + r * 512 + c8 * 8);
    int off = (r << 8) + (c8 << 4); off ^= (r & 7) << 4;
    *(bf16x8*)(kbuf + off) = v;
  }
  // stage V transposed: thread (tok = tid&63, dg = tid>>6) reads 32 d's of
  // its token (64B contiguous), writes Vt[d][tok]
  {
    int tok = tid & 63;
    int dg  = tid >> 6;            // 0..3 -> d = dg*32 .. +31
    bf16x8 vv[4];
    #pragma unroll
    for (int s = 0; s < 4; ++s)
      vv[s] = *(const bf16x8*)(Vs + tok * 512 + dg * 32 + s * 8);
    #pragma unroll
    for (int s = 0; s < 4; ++s)
      #pragma unroll
      for (int e = 0; e < 8; ++e) {
        int d = dg * 32 + s * 8 + e;
        int off = (d << 7) + (tok << 1); off ^= (d & 7) << 4;
        *(unsigned short*)(vtb + off) = (unsigned short)vv[s][e];
      }
  }
  __syncthreads();

  // QK^T: wave owns 16 q-rows; Q read straight from slab
  f32x4 sacc[4];
  #pragma unroll
  for (int nt = 0; nt < 4; ++nt) sacc[nt] = (f32x4){0.f, 0.f, 0.f, 0.f};
  #pragma unroll
  for (int kk = 0; kk < 128; kk += 32) {
    int ka = kk + kl;
    bf16x8 afr = *(const bf16x8*)(Qs + (wvid * 16 + l15) * 512 + ka);
    #pragma unroll
    for (int nt = 0; nt < 4; ++nt) {
      int jr = nt * 16 + l15;
      int o2 = (jr << 8) + (ka << 1); o2 ^= (jr & 7) << 4;
      bf16x8 bfr = *(const bf16x8*)(kbuf + o2);
      sacc[nt] = __builtin_amdgcn_mfma_f32_16x16x32_bf16(afr, bfr, sacc[nt], 0, 0, 0);
    }
  }
  // softmax (each row lives in one 16-lane group), P -> LDS
  #pragma unroll
  for (int rg = 0; rg < 4; ++rg) {
    float m = -3.0e38f;
    #pragma unroll
    for (int nt = 0; nt < 4; ++nt) m = fmaxf(m, sacc[nt][rg]);
    #pragma unroll
    for (int dd = 1; dd < 16; dd <<= 1) m = fmaxf(m, __shfl_xor(m, dd, 64));
    float s = 0.f, e[4];
    #pragma unroll
    for (int nt = 0; nt < 4; ++nt) { e[nt] = __expf((sacc[nt][rg] - m) * SCALE); s += e[nt]; }
    #pragma unroll
    for (int dd = 1; dd < 16; dd <<= 1) s += __shfl_xor(s, dd, 64);
    float inv = 1.f / s;
    int row = wvid * 16 + rbase + rg;
    #pragma unroll
    for (int nt = 0; nt < 4; ++nt) {
      int col = nt * 16 + l15;
      int off = (row << 7) + (col << 1); off ^= (row & 7) << 4;
      *(unsigned short*)(pbf + off) = f2b(e[nt] * inv);
    }
  }
  __syncthreads();

  // PV: all 64 rows x wave's 32 d-cols, K=64
  f32x4 pacc[4][2];
  #pragma unroll
  for (int mt = 0; mt < 4; ++mt)
    #pragma unroll
    for (int nt = 0; nt < 2; ++nt) pacc[mt][nt] = (f32x4){0.f, 0.f, 0.f, 0.f};
  #pragma unroll
  for (int kk = 0; kk < 64; kk += 32) {
    int ka = kk + kl;
    bf16x8 afr[4];
    #pragma unroll
    for (int mt = 0; mt < 4; ++mt) {
      int row = mt * 16 + l15;
      int off = (row << 7) + (ka << 1); off ^= (row & 7) << 4;
      afr[mt] = *(const bf16x8*)(pbf + off);
    }
    bf16x8 bfr[2];
    #pragma unroll
    for (int nt = 0; nt < 2; ++nt) {
      int d = wvid * 32 + nt * 16 + l15;
      int off = (d << 7) + (ka << 1); off ^= (d & 7) << 4;
      bfr[nt] = *(const bf16x8*)(vtb + off);
    }
    #pragma unroll
    for (int mt = 0; mt < 4; ++mt)
      #pragma unroll
      for (int nt = 0; nt < 2; ++nt)
        pacc[mt][nt] = __builtin_amdgcn_mfma_f32_16x16x32_bf16(afr[mt], bfr[nt], pacc[mt][nt], 0, 0, 0);
  }
  // write attn over the Q slice (this block is its only reader)
  #pragma unroll
  for (int nt = 0; nt < 2; ++nt) {
    int d = wvid * 32 + nt * 16 + l15;
    #pragma unroll
    for (int mt = 0; mt < 4; ++mt)
      #pragma unroll
      for (int rg = 0; rg < 4; ++rg) {
        int row = mt * 16 + rbase + rg;
        Qs[row * 512 + d] = f2b(pacc[mt][nt][rg]);
      }
  }
}

// ============ K3: out = slab @ Wo^T + bo (window-ordered slab) ==============
extern "C" __global__ __launch_bounds__(256, 2)
void proj_o(const unsigned short* __restrict__ slab,
            const unsigned short* __restrict__ wo,
            const float* __restrict__ bo,
            float* __restrict__ out)
{
  __shared__ char smem[65536];                 // [64][512] bf16, swizzled
  const int tid   = threadIdx.x;
  const int wvid  = tid >> 6;
  const int lane  = tid & 63;
  const int l15   = lane & 15;
  const int kl    = (lane >> 4) << 3;
  const int rbase = (lane >> 4) << 2;

  const int blk = blockIdx.x;
  const int b   = blk / NWIN;
  const int w   = blk - b * NWIN;
  const int wy  = w / GWt, wx = w - wy * GWt;

  const unsigned short* src = slab + (size_t)blk * 32768;
  for (int it = 0; it < 16; ++it) {
    int f  = it * 256 + tid;                   // u16x8 group; 64 per row
    int r  = f >> 6;
    int c8 = f & 63;
    bf16x8 v = *(const bf16x8*)(src + r * 512 + c8 * 8);
    int off = (r << 10) + (c8 << 4);
    off ^= (r & 7) << 4;
    *(bf16x8*)(smem + off) = v;
  }
  __syncthreads();

  for (int half = 0; half < 2; ++half) {
    f32x4 acc[4][4];
    #pragma unroll
    for (int mt = 0; mt < 4; ++mt)
      #pragma unroll
      for (int nt = 0; nt < 4; ++nt) acc[mt][nt] = (f32x4){0.f, 0.f, 0.f, 0.f};
    #pragma unroll 2
    for (int kk = 0; kk < 512; kk += 32) {
      int ka = kk + kl;
      bf16x8 afr[4];
      #pragma unroll
      for (int mt = 0; mt < 4; ++mt) {
        int row = mt * 16 + l15;
        int off = (row << 10) + (ka << 1); off ^= (row & 7) << 4;
        afr[mt] = *(const bf16x8*)(smem + off);
      }
      bf16x8 bfr[4];
      #pragma unroll
      for (int nt = 0; nt < 4; ++nt) {
        int j = wvid * 128 + half * 64 + nt * 16 + l15;
        bfr[nt] = *(const bf16x8*)(wo + (size_t)j * 512 + ka);
      }
      #pragma unroll
      for (int mt = 0; mt < 4; ++mt)
        #pragma unroll
        for (int nt = 0; nt < 4; ++nt)
          acc[mt][nt] = __builtin_amdgcn_mfma_f32_16x16x32_bf16(afr[mt], bfr[nt], acc[mt][nt], 0, 0, 0);
    }
    #pragma unroll
    for (int mt = 0; mt < 4; ++mt)
      #pragma unroll
      for (int rg = 0; rg < 4; ++rg) {
        int r = mt * 16 + rbase + rg;
        int gy = wy * 8 + (r >> 3), gx = wx * 8 + (r & 7);
        if (gy < Ht && gx < Wt) {
          float* po = out + ((size_t)b * NTOK + gy * Wt + gx) * C;
          #pragma unroll
          for (int nt = 0; nt < 4; ++nt) {
            int j = wvid * 128 + half * 64 + nt * 16 + l15;
            po[j] = acc[mt][nt][rg] + bo[j];
          }
        }
      }
  }
}

// ============ TIER 2: round-7 fused per-window kernel (proven, 119MB ws) ====
extern "C" __global__ __launch_bounds__(256, 1)
void qkv_attn(const float* __restrict__ x,
              const unsigned short* __restrict__ wbf,
              const float* __restrict__ bq, const float* __restrict__ bk,
              const float* __restrict__ bv,
              unsigned short* __restrict__ slab)
{
  __shared__ char smem[73728];
  char* qb = smem + 32768;
  char* kb = smem + 49152;
  char* pb = smem + 65536;

  const int tid   = threadIdx.x;
  const int wvid  = tid >> 6;
  const int lane  = tid & 63;
  const int l15   = lane & 15;
  const int kl    = (lane >> 4) << 3;
  const int rbase = (lane >> 4) << 2;

  const int blk = blockIdx.x;
  const int b   = blk / NWIN;
  const int w   = blk - b * NWIN;
  const int wy  = w / GWt, wx = w - wy * GWt;

  for (int it = 0; it < 32; ++it) {
    int f  = it * 256 + tid;
    int r  = f >> 7;
    int c4 = f & 127;
    int gy = wy * 8 + (r >> 3), gx = wx * 8 + (r & 7);
    float4 v = make_float4(0.f, 0.f, 0.f, 0.f);
    if (gy < Ht && gx < Wt)
      v = *(const float4*)(x + ((size_t)b * NTOK + gy * Wt + gx) * C + c4 * 4);
    u16x4 o;
    o[0] = f2b(v.x); o[1] = f2b(v.y); o[2] = f2b(v.z); o[3] = f2b(v.w);
    int lc  = c4 & 63;
    int off = (r << 9) + (lc << 3);
    off ^= (r & 7) << 4;
    off += (c4 >> 6) * 32768;
    *(u16x4*)(smem + off) = o;
  }
  __syncthreads();

  bf16x8 xr[4][8];
  #pragma unroll
  for (int mt = 0; mt < 4; ++mt) {
    int row = mt * 16 + l15;
    #pragma unroll
    for (int s = 0; s < 8; ++s) {
      int off = (row << 9) + ((s * 32 + kl) << 1);
      off ^= (row & 7) << 4;
      xr[mt][s] = *(const bf16x8*)(smem + 32768 + off);
    }
  }
  __syncthreads();

  auto gemm_r = [&](const unsigned short* wm, int h, f32x4 (&acc)[4][2]) {
    #pragma unroll
    for (int mt = 0; mt < 4; ++mt)
      #pragma unroll
      for (int nt = 0; nt < 2; ++nt) acc[mt][nt] = (f32x4){0.f, 0.f, 0.f, 0.f};
    #pragma unroll
    for (int s = 0; s < 16; ++s) {
      int ka = s * 32 + kl;
      bf16x8 afr[4];
      if (s < 8) {
        #pragma unroll
        for (int mt = 0; mt < 4; ++mt) {
          int row = mt * 16 + l15;
          int off = (row << 9) + (ka << 1);
          off ^= (row & 7) << 4;
          afr[mt] = *(const bf16x8*)(smem + off);
        }
      } else {
        #pragma unroll
        for (int mt = 0; mt < 4; ++mt) afr[mt] = xr[mt][s - 8];
      }
      bf16x8 bfr[2];
      #pragma unroll
      for (int nt = 0; nt < 2; ++nt) {
        int jg = h * 128 + wvid * 32 + nt * 16 + l15;
        bfr[nt] = *(const bf16x8*)(wm + (size_t)jg * 512 + ka);
      }
      #pragma unroll
      for (int mt = 0; mt < 4; ++mt)
        #pragma unroll
        for (int nt = 0; nt < 2; ++nt)
          acc[mt][nt] = __builtin_amdgcn_mfma_f32_16x16x32_bf16(afr[mt], bfr[nt], acc[mt][nt], 0, 0, 0);
    }
  };

  auto store_rm = [&](f32x4 (&acc)[4][2], char* base, const float* bias, int h) {
    #pragma unroll
    for (int nt = 0; nt < 2; ++nt) {
      int col = wvid * 32 + nt * 16 + l15;
      float bi = bias[h * 128 + col];
      #pragma unroll
      for (int mt = 0; mt < 4; ++mt)
        #pragma unroll
        for (int rg = 0; rg < 4; ++rg) {
          int row = mt * 16 + rbase + rg;
          int off = (row << 8) + (col << 1);
          off ^= (row & 7) << 4;
          *(unsigned short*)(base + off) = f2b(acc[mt][nt][rg] + bi);
        }
    }
  };

  unsigned short* sl = slab + (size_t)blk * 32768;

  for (int h = 0; h < 4; ++h) {
    {
      f32x4 acc[4][2];
      gemm_r(wbf + 0 * 262144, h, acc);
      store_rm(acc, qb, bq, h);
      gemm_r(wbf + 1 * 262144, h, acc);
      store_rm(acc, kb, bk, h);
    }
    __syncthreads();
    f32x4 vacc[4][2];
    {
      f32x4 sacc[4];
      #pragma unroll
      for (int nt = 0; nt < 4; ++nt) sacc[nt] = (f32x4){0.f, 0.f, 0.f, 0.f};
      #pragma unroll
      for (int kk = 0; kk < 128; kk += 32) {
        int ka = kk + kl;
        int row = wvid * 16 + l15;
        int off = (row << 8) + (ka << 1); off ^= (row & 7) << 4;
        bf16x8 afr = *(const bf16x8*)(qb + off);
        #pragma unroll
        for (int nt = 0; nt < 4; ++nt) {
          int jr = nt * 16 + l15;
          int o2 = (jr << 8) + (ka << 1); o2 ^= (jr & 7) << 4;
          bf16x8 bfr = *(const bf16x8*)(kb + o2);
          sacc[nt] = __builtin_amdgcn_mfma_f32_16x16x32_bf16(afr, bfr, sacc[nt], 0, 0, 0);
        }
      }
      #pragma unroll
      for (int rg = 0; rg < 4; ++rg) {
        float m = -3.0e38f;
        #pragma unroll
        for (int nt = 0; nt < 4; ++nt) m = fmaxf(m, sacc[nt][rg]);
        #pragma unroll
        for (int dd = 1; dd < 16; dd <<= 1) m = fmaxf(m, __shfl_xor(m, dd, 64));
        float s = 0.f, e[4];
        #pragma unroll
        for (int nt = 0; nt < 4; ++nt) { e[nt] = __expf((sacc[nt][rg] - m) * SCALE); s += e[nt]; }
        #pragma unroll
        for (int dd = 1; dd < 16; dd <<= 1) s += __shfl_xor(s, dd, 64);
        float inv = 1.f / s;
        int row = wvid * 16 + rbase + rg;
        #pragma unroll
        for (int nt = 0; nt < 4; ++nt) {
          int col = nt * 16 + l15;
          int off = (row << 7) + (col << 1); off ^= (row & 7) << 4;
          *(unsigned short*)(pb + off) = f2b(e[nt] * inv);
        }
      }
      gemm_r(wbf + 2 * 262144, h, vacc);
    }
    __syncthreads();
    {
      #pragma unroll
      for (int nt = 0; nt < 2; ++nt) {
        int d = wvid * 32 + nt * 16 + l15;
        float bi = bv[h * 128 + d];
        #pragma unroll
        for (int mt = 0; mt < 4; ++mt) {
          int j0 = mt * 16 + rbase;
          u16x4 pk;
          #pragma unroll
          for (int rg = 0; rg < 4; ++rg) pk[rg] = f2b(vacc[mt][nt][rg] + bi);
          int off = (d << 7) + (j0 << 1); off ^= (d & 7) << 4;
          *(u16x4*)(kb + off) = pk;
        }
      }
    }
    __syncthreads();
    {
      f32x4 pacc[4][2];
      #pragma unroll
      for (int mt = 0; mt < 4; ++mt)
        #pragma unroll
        for (int nt = 0; nt < 2; ++nt) pacc[mt][nt] = (f32x4){0.f, 0.f, 0.f, 0.f};
      #pragma unroll
      for (int kk = 0; kk < 64; kk += 32) {
        int ka = kk + kl;
        bf16x8 afr[4];
        #pragma unroll
        for (int mt = 0; mt < 4; ++mt) {
          int row = mt * 16 + l15;
          int off = (row << 7) + (ka << 1); off ^= (row & 7) << 4;
          afr[mt] = *(const bf16x8*)(pb + off);
        }
        bf16x8 bfr[2];
        #pragma unroll
        for (int nt = 0; nt < 2; ++nt) {
          int d = wvid * 32 + nt * 16 + l15;
          int off = (d << 7) + (ka << 1); off ^= (d & 7) << 4;
          bfr[nt] = *(const bf16x8*)(kb + off);
        }
        #pragma unroll
        for (int mt = 0; mt < 4; ++mt)
          #pragma unroll
          for (int nt = 0; nt < 2; ++nt)
            pacc[mt][nt] = __builtin_amdgcn_mfma_f32_16x16x32_bf16(afr[mt], bfr[nt], pacc[mt][nt], 0, 0, 0);
      }
      #pragma unroll
      for (int nt = 0; nt < 2; ++nt) {
        int d = wvid * 32 + nt * 16 + l15;
        #pragma unroll
        for (int mt = 0; mt < 4; ++mt)
          #pragma unroll
          for (int rg = 0; rg < 4; ++rg) {
            int row = mt * 16 + rbase + rg;
            sl[row * 512 + h * 128 + d] = f2b(pacc[mt][nt][rg]);
          }
      }
    }
    __syncthreads();
  }
}

extern "C" void kernel_launch(void* const* d_in, const int* in_sizes, int n_in,
                              void* d_out, int out_size, void* d_ws, size_t ws_size,
                              hipStream_t stream) {
  const float* x  = (const float*)d_in[0];
  const float* Wq = (const float*)d_in[2];
  const float* bq = (const float*)d_in[3];
  const float* Wk = (const float*)d_in[4];
  const float* bk = (const float*)d_in[5];
  const float* Wv = (const float*)d_in[6];
  const float* bv = (const float*)d_in[7];
  const float* Wo = (const float*)d_in[8];
  const float* bo = (const float*)d_in[9];
  unsigned short* wbf = (unsigned short*)d_ws;

  cvt_weights<<<1024, 256, 0, stream>>>(Wq, Wk, Wv, Wo, wbf);

  const size_t need_full = (WOFF + 3 * SLABE) * 2;  // ~354 MB
  if (ws_size >= need_full) {
    unsigned short* qs = wbf + WOFF;
    unsigned short* ks = qs + SLABE;
    unsigned short* vs = ks + SLABE;
    qkv_gemm<<<NBLK, 256, 0, stream>>>(x, wbf, bq, bk, bv, qs, ks, vs);
    attn2<<<dim3(NBLK, 4), 256, 0, stream>>>(qs, ks, vs);
    proj_o<<<NBLK, 256, 0, stream>>>(qs, wbf + 3 * 262144, bo, (float*)d_out);
  } else {
    // tier 2: proven round-7 path (works from 119 MB ws)
    unsigned short* slab = wbf + WOFF;
    qkv_attn<<<NBLK, 256, 0, stream>>>(x, wbf, bq, bk, bv, slab);
    proj_o<<<NBLK, 256, 0, stream>>>(slab, wbf + 3 * 262144, bo, (float*)d_out);
  }
}